// Round 3
// baseline (2833.008 us; speedup 1.0000x reference)
//
#include <hip/hip_runtime.h>
#include <hip/hip_bf16.h>
#include <stdint.h>

// GNN_758: stacked RelGraphConv x2.  N=50000, E=1.6M, D=128, R=20.
// agg[dst] = sum_r (sum_{e in rel r -> dst} h[src]) @ W[r]; self-loop = rel 20.
// R3: phase-1 gather MLP fix — 4-deep unrolled independent row loads per wave,
// 512 threads/block (8 waves, 24 waves/CU). Phase 2 splits K(x4) and N(x2).

#define NN 50000
#define NE 1600000
#define DIM 128
#define NREL 20
#define NRELP 21
#define TILE 16
#define NTILE (NN / TILE)        // 3125
#define NBUCKET (NTILE * 4)      // 12500 (tile, rel-chunk)
#define STR_R 132                // rel slot stride in floats
#define STR_D 812                // per-dst stride = 6*132 + 20
#define PACKED_ELEMS (2 * NRELP * 4 * 8 * 64 * 8)   // 688128

typedef __attribute__((ext_vector_type(8))) short short8;
typedef __attribute__((ext_vector_type(4))) float f32x4;

__device__ __forceinline__ unsigned short f32_to_bf16_raw(float f) {
  union { float f; unsigned u; } c; c.f = f;
  unsigned u = c.u;
  return (unsigned short)((u + 0x7fffu + ((u >> 16) & 1u)) >> 16);  // RNE
}
__device__ __forceinline__ float bf16_raw_to_f32(unsigned short s) {
  union { unsigned u; float f; } c; c.u = ((unsigned)s) << 16;
  return c.f;
}

// ---------------- fp32 -> bf16 (x4) ----------------
__global__ void cvt_bf16_kernel(const float* __restrict__ in,
                                unsigned short* __restrict__ out, int n4) {
  int i = blockIdx.x * 256 + threadIdx.x;
  if (i < n4) {
    float4 f = ((const float4*)in)[i];
    short4 o;
    o.x = (short)f32_to_bf16_raw(f.x);
    o.y = (short)f32_to_bf16_raw(f.y);
    o.z = (short)f32_to_bf16_raw(f.z);
    o.w = (short)f32_to_bf16_raw(f.w);
    ((short4*)out)[i] = o;
  }
}

// ---------------- pack W (+loop_w as rel 20) into B-fragment order ----------------
// WP flat: ((((l*21 + r)*4 + ks)*8 + nc)*64 + lane)*8 + j  (verified R0/R1)
__global__ void pack_w_kernel(const float* __restrict__ W,
                              const float* __restrict__ loop_w,
                              unsigned short* __restrict__ WP) {
  int idx = blockIdx.x * 256 + threadIdx.x;
  if (idx >= PACKED_ELEMS) return;
  int j = idx & 7;       int t = idx >> 3;
  int lane = t & 63;     t >>= 6;
  int nc = t & 7;        t >>= 3;
  int ks = t & 3;        t >>= 2;
  int r = t % NRELP;     int l = t / NRELP;
  int k = ks * 32 + (lane >> 4) * 8 + j;
  int n = nc * 16 + (lane & 15);
  float v = (r < NREL) ? W[(((size_t)l * NREL + r) * DIM + k) * DIM + n]
                       : loop_w[((size_t)l * DIM + k) * DIM + n];
  WP[idx] = f32_to_bf16_raw(v);
}

// ---------------- edge bucketing by (dst_tile, rel_chunk) ----------------
__global__ void hist_kernel(const int* __restrict__ dst, const int* __restrict__ et,
                            unsigned int* __restrict__ counts, int n) {
  int i = blockIdx.x * 256 + threadIdx.x;
  if (i < n) {
    int b = (dst[i] >> 4) * 4 + (et[i] / 5);
    atomicAdd(&counts[b], 1u);
  }
}

__global__ void scan_kernel(const unsigned int* __restrict__ counts,
                            unsigned int* __restrict__ ofs,
                            unsigned int* __restrict__ cursor) {
  __shared__ unsigned int buf[1024];
  __shared__ unsigned int carry;
  int t = threadIdx.x;
  if (t == 0) carry = 0;
  __syncthreads();
  for (int base = 0; base < NBUCKET; base += 1024) {
    int i = base + t;
    unsigned int v = (i < NBUCKET) ? counts[i] : 0u;
    buf[t] = v;
    __syncthreads();
    for (int d = 1; d < 1024; d <<= 1) {
      unsigned int add = (t >= d) ? buf[t - d] : 0u;
      __syncthreads();
      buf[t] += add;
      __syncthreads();
    }
    unsigned int excl = buf[t] - v + carry;
    if (i < NBUCKET) { ofs[i] = excl; cursor[i] = excl; }
    __syncthreads();
    if (t == 1023) carry += buf[1023];
    __syncthreads();
  }
  if (t == 0) ofs[NBUCKET] = carry;
}

// pack: src(16b) | rel_local(3b)<<16 | dst_local(4b)<<19
__global__ void scatter_kernel(const int* __restrict__ src, const int* __restrict__ dst,
                               const int* __restrict__ et,
                               unsigned int* __restrict__ cursor,
                               unsigned int* __restrict__ epk, int n) {
  int i = blockIdx.x * 256 + threadIdx.x;
  if (i < n) {
    int d = dst[i], e = et[i];
    int b = (d >> 4) * 4 + (e / 5);
    unsigned int pos = atomicAdd(&cursor[b], 1u);
    epk[pos] = (unsigned int)src[i] | ((unsigned int)(e % 5) << 16)
             | ((unsigned int)(d & 15) << 19);
  }
}

// one edge's scatter-accumulate: 16 lanes (m) x 8 elems, bank-rotated
__device__ __forceinline__ void edge_atomic(float S[TILE][STR_D], unsigned int pk,
                                            short8 hv, int m) {
  int rl = (int)((pk >> 16) & 7u);
  int d  = (int)((pk >> 19) & 15u);
  float* base = &S[d][rl * STR_R + m * 8];
#pragma unroll
  for (int jj = 0; jj < 8; ++jj) {
    int j = (jj + m) & 7;
    atomicAdd(base + j, bf16_raw_to_f32((unsigned short)hv[j]));
  }
}

// ---------------- fused RGCN layer ----------------
// 3125 blocks x 512 threads (8 waves). LDS ~51 KB -> 3 blocks/CU, 24 waves/CU.
__global__ __launch_bounds__(512) void rgcn_layer_kernel(
    const unsigned short* __restrict__ hb,    // [N,128] bf16
    const unsigned short* __restrict__ WP,    // packed weights
    const float* __restrict__ bias,           // [128] this layer
    int layer,
    const unsigned int* __restrict__ bofs,    // [NBUCKET+1]
    const unsigned int* __restrict__ epk,     // [E] packed, bucket-sorted
    float* __restrict__ out)                  // [N,128] fp32
{
  __shared__ __align__(16) float S[TILE][STR_D];   // 51968 B
  __shared__ unsigned int bofs_l[5];

  const int tid  = threadIdx.x;
  const int lane = tid & 63;
  const int w    = tid >> 6;        // wave 0..7
  const int quad = lane >> 4;
  const int m    = lane & 15;
  const int gi   = w * 4 + quad;    // 16-lane group id 0..31
  const int kc   = w & 3;           // phase-2 k-chunk
  const int nh   = w >> 2;          // phase-2 n-half
  const int dst_base = blockIdx.x * TILE;

  if (tid < 5) bofs_l[tid] = bofs[blockIdx.x * 4 + tid];

  f32x4 acc[4];
#pragma unroll
  for (int nc = 0; nc < 4; ++nc) acc[nc] = (f32x4){0.f, 0.f, 0.f, 0.f};

  for (int c = 0; c < 4; ++c) {
    const int rbase = c * 5;
    const int rc = (c == 3) ? 6 : 5;

    // zero atomic-target slots 0..4 (2560 float4 / 512 thr = 5 each)
    for (int t = tid; t < TILE * 5 * 32; t += 512) {
      int d = t / 160, rem = t - d * 160;
      int rl = rem >> 5, kq = rem & 31;
      *(float4*)&S[d][rl * STR_R + kq * 4] = (float4){0.f, 0.f, 0.f, 0.f};
    }
    // self-loop rows into slot 5 (chunk 3 only)
    if (c == 3 && tid < 256) {
      int d = tid >> 4, mm = tid & 15;
      short8 hv = *(const short8*)(hb + (size_t)(dst_base + d) * DIM + mm * 8);
      float4 f0, f1;
      f0.x = bf16_raw_to_f32((unsigned short)hv[0]);
      f0.y = bf16_raw_to_f32((unsigned short)hv[1]);
      f0.z = bf16_raw_to_f32((unsigned short)hv[2]);
      f0.w = bf16_raw_to_f32((unsigned short)hv[3]);
      f1.x = bf16_raw_to_f32((unsigned short)hv[4]);
      f1.y = bf16_raw_to_f32((unsigned short)hv[5]);
      f1.z = bf16_raw_to_f32((unsigned short)hv[6]);
      f1.w = bf16_raw_to_f32((unsigned short)hv[7]);
      *(float4*)&S[d][5 * STR_R + mm * 8]     = f0;
      *(float4*)&S[d][5 * STR_R + mm * 8 + 4] = f1;
    }
    __syncthreads();

    // phase 1: 32 groups x 4-deep unrolled independent row gathers.
    // Group gi takes edges cbeg+gi, +32, +64, ... ; unrolled x4 (stride 128).
    {
      const int cbeg = (int)bofs_l[c], cend = (int)bofs_l[c + 1];
      int e = cbeg + gi;
      for (; e + 96 < cend; e += 128) {
        unsigned int pk0 = epk[e];
        unsigned int pk1 = epk[e + 32];
        unsigned int pk2 = epk[e + 64];
        unsigned int pk3 = epk[e + 96];
        const short8* r0 = (const short8*)(hb + (size_t)(pk0 & 0xffffu) * DIM + m * 8);
        const short8* r1 = (const short8*)(hb + (size_t)(pk1 & 0xffffu) * DIM + m * 8);
        const short8* r2 = (const short8*)(hb + (size_t)(pk2 & 0xffffu) * DIM + m * 8);
        const short8* r3 = (const short8*)(hb + (size_t)(pk3 & 0xffffu) * DIM + m * 8);
        short8 h0 = *r0, h1 = *r1, h2 = *r2, h3 = *r3;   // 4 loads in flight
        edge_atomic(S, pk0, h0, m);
        edge_atomic(S, pk1, h1, m);
        edge_atomic(S, pk2, h2, m);
        edge_atomic(S, pk3, h3, m);
      }
      for (; e < cend; e += 32) {
        unsigned int pk = epk[e];
        short8 hv = *(const short8*)(hb + (size_t)(pk & 0xffffu) * DIM + m * 8);
        edge_atomic(S, pk, hv, m);
      }
    }
    __syncthreads();

    // phase 2: wave owns (k-chunk kc, n-half nh). A-frag reused for 4 nc.
    for (int rl = 0; rl < rc; ++rl) {
      const int r = rbase + rl;
      const float* ap = &S[m][rl * STR_R + kc * 32 + quad * 8];
      float4 f0 = *(const float4*)ap;
      float4 f1 = *(const float4*)(ap + 4);
      short8 a;
      a[0] = (short)f32_to_bf16_raw(f0.x);
      a[1] = (short)f32_to_bf16_raw(f0.y);
      a[2] = (short)f32_to_bf16_raw(f0.z);
      a[3] = (short)f32_to_bf16_raw(f0.w);
      a[4] = (short)f32_to_bf16_raw(f1.x);
      a[5] = (short)f32_to_bf16_raw(f1.y);
      a[6] = (short)f32_to_bf16_raw(f1.z);
      a[7] = (short)f32_to_bf16_raw(f1.w);
      const unsigned short* bp =
          WP + ((((size_t)(layer * NRELP + r) * 4 + kc) * 8 + nh * 4) * 64 + lane) * 8;
#pragma unroll
      for (int nc = 0; nc < 4; ++nc) {
        short8 b = *(const short8*)(bp + (size_t)nc * 64 * 8);
        acc[nc] = __builtin_amdgcn_mfma_f32_16x16x32_bf16(a, b, acc[nc], 0, 0, 0);
      }
    }
    __syncthreads();
  }

  // cross-wave K-reduction through LDS. red[kc][row16][132] (nh halves disjoint cols)
  float* red = &S[0][0];
#pragma unroll
  for (int nc = 0; nc < 4; ++nc)
#pragma unroll
    for (int i = 0; i < 4; ++i)
      red[kc * (16 * 132) + (quad * 4 + i) * 132 + nh * 64 + nc * 16 + m] = acc[nc][i];
  __syncthreads();

  {
    int row = tid >> 5, cb = (tid & 31) * 4;   // 16 rows x 128 cols / 512 thr
    float4 bv = *(const float4*)(bias + cb);
    float o[4];
#pragma unroll
    for (int j = 0; j < 4; ++j) {
      int col = cb + j;
      o[j] = red[0 * 2112 + row * 132 + col] + red[1 * 2112 + row * 132 + col]
           + red[2 * 2112 + row * 132 + col] + red[3 * 2112 + row * 132 + col];
    }
    o[0] += bv.x; o[1] += bv.y; o[2] += bv.z; o[3] += bv.w;
    float* op = out + (size_t)(dst_base + row) * DIM + cb;
    *(float4*)op = (float4){o[0], o[1], o[2], o[3]};
  }
}

// ---------------- launch ----------------
extern "C" void kernel_launch(void* const* d_in, const int* in_sizes, int n_in,
                              void* d_out, int out_size, void* d_ws, size_t ws_size,
                              hipStream_t stream) {
  const float* h0     = (const float*)d_in[0];
  const float* W      = (const float*)d_in[1];
  const float* loop_w = (const float*)d_in[2];
  const float* bias   = (const float*)d_in[3];
  const int* esrc     = (const int*)d_in[4];
  const int* edst     = (const int*)d_in[5];
  const int* etyp     = (const int*)d_in[6];
  float* out = (float*)d_out;

  char* ws = (char*)d_ws;
  size_t off = 0;
  auto alloc = [&](size_t bytes) -> void* {
    void* p = ws + off;
    off = (off + bytes + 255) & ~(size_t)255;
    return p;
  };
  unsigned short* h_bf16 = (unsigned short*)alloc((size_t)NN * DIM * 2);
  unsigned short* WP     = (unsigned short*)alloc((size_t)PACKED_ELEMS * 2);
  float*          h1     = (float*)alloc((size_t)NN * DIM * 4);
  unsigned int*   counts = (unsigned int*)alloc((size_t)NBUCKET * 4);
  unsigned int*   bofs   = (unsigned int*)alloc((size_t)(NBUCKET + 1) * 4);
  unsigned int*   cursor = (unsigned int*)alloc((size_t)NBUCKET * 4);
  unsigned int*   epk    = (unsigned int*)alloc((size_t)NE * 4);

  hipMemsetAsync(counts, 0, (size_t)NBUCKET * 4, stream);
  hist_kernel<<<NE / 256, 256, 0, stream>>>(edst, etyp, counts, NE);
  scan_kernel<<<1, 1024, 0, stream>>>(counts, bofs, cursor);
  scatter_kernel<<<NE / 256, 256, 0, stream>>>(esrc, edst, etyp, cursor, epk, NE);

  pack_w_kernel<<<(PACKED_ELEMS + 255) / 256, 256, 0, stream>>>(W, loop_w, WP);

  cvt_bf16_kernel<<<(NN * DIM / 4 + 255) / 256, 256, 0, stream>>>(h0, h_bf16, NN * DIM / 4);
  rgcn_layer_kernel<<<NTILE, 512, 0, stream>>>(h_bf16, WP, bias, 0, bofs, epk, h1);

  cvt_bf16_kernel<<<(NN * DIM / 4 + 255) / 256, 256, 0, stream>>>(h1, h_bf16, NN * DIM / 4);
  rgcn_layer_kernel<<<NTILE, 512, 0, stream>>>(h_bf16, WP, bias + DIM, 1, bofs, epk, out);
}

// Round 5
// 2632.359 us; speedup vs baseline: 1.0762x; 1.0762x over previous
//
#include <hip/hip_runtime.h>
#include <hip/hip_bf16.h>
#include <stdint.h>

// GNN_758: stacked RelGraphConv x2.  N=50000, E=1.6M, D=128, R=20.
// agg[dst] = sum_r (sum_{e in rel r -> dst} h[src]) @ W[r]; self-loop = rel 20.
// R5 (= R4 + compile fix): phase-1 gather via global_load_lds DMA (12 rows in
// flight per wave; no register consumer so the compiler can't serialize),
// nontemporal hb stores (clean lines -> L3, avoid cross-XCD dirty-line trips).

#define NN 50000
#define NE 1600000
#define DIM 128
#define NREL 20
#define NRELP 21
#define TILE 16
#define NTILE (NN / TILE)        // 3125
#define NBUCKET (NTILE * 4)      // 12500 (tile, rel-chunk)
#define STR_R 132                // rel slot stride in floats
#define STR_D 812                // per-dst stride = 6*132 + 20
#define PACKED_ELEMS (2 * NRELP * 4 * 8 * 64 * 8)   // 688128

typedef __attribute__((ext_vector_type(8))) short short8;
typedef __attribute__((ext_vector_type(4))) float f32x4;
typedef const __attribute__((address_space(1))) unsigned int* gas_u32p;
typedef __attribute__((address_space(3))) unsigned int* las_u32p;

__device__ __forceinline__ unsigned short f32_to_bf16_raw(float f) {
  union { float f; unsigned u; } c; c.f = f;
  unsigned u = c.u;
  return (unsigned short)((u + 0x7fffu + ((u >> 16) & 1u)) >> 16);  // RNE
}
__device__ __forceinline__ float bf16_raw_to_f32(unsigned short s) {
  union { unsigned u; float f; } c; c.u = ((unsigned)s) << 16;
  return c.f;
}

// ---------------- fp32 -> bf16 (x4), nontemporal stores ----------------
__global__ void cvt_bf16_kernel(const float* __restrict__ in,
                                unsigned short* __restrict__ out, int n4) {
  int i = blockIdx.x * 256 + threadIdx.x;
  if (i < n4) {
    float4 f = ((const float4*)in)[i];
    unsigned long long p =
        (unsigned long long)f32_to_bf16_raw(f.x)
      | ((unsigned long long)f32_to_bf16_raw(f.y) << 16)
      | ((unsigned long long)f32_to_bf16_raw(f.z) << 32)
      | ((unsigned long long)f32_to_bf16_raw(f.w) << 48);
    __builtin_nontemporal_store(p, (unsigned long long*)out + i);  // clean -> L3
  }
}

// ---------------- pack W (+loop_w as rel 20) into B-fragment order ----------------
// WP flat: ((((l*21 + r)*4 + ks)*8 + nc)*64 + lane)*8 + j  (verified R0/R1)
__global__ void pack_w_kernel(const float* __restrict__ W,
                              const float* __restrict__ loop_w,
                              unsigned short* __restrict__ WP) {
  int idx = blockIdx.x * 256 + threadIdx.x;
  if (idx >= PACKED_ELEMS) return;
  int j = idx & 7;       int t = idx >> 3;
  int lane = t & 63;     t >>= 6;
  int nc = t & 7;        t >>= 3;
  int ks = t & 3;        t >>= 2;
  int r = t % NRELP;     int l = t / NRELP;
  int k = ks * 32 + (lane >> 4) * 8 + j;
  int n = nc * 16 + (lane & 15);
  float v = (r < NREL) ? W[(((size_t)l * NREL + r) * DIM + k) * DIM + n]
                       : loop_w[((size_t)l * DIM + k) * DIM + n];
  WP[idx] = f32_to_bf16_raw(v);
}

// ---------------- edge bucketing by (dst_tile, rel_chunk) ----------------
__global__ void hist_kernel(const int* __restrict__ dst, const int* __restrict__ et,
                            unsigned int* __restrict__ counts, int n) {
  int i = blockIdx.x * 256 + threadIdx.x;
  if (i < n) {
    int b = (dst[i] >> 4) * 4 + (et[i] / 5);
    atomicAdd(&counts[b], 1u);
  }
}

__global__ void scan_kernel(const unsigned int* __restrict__ counts,
                            unsigned int* __restrict__ ofs,
                            unsigned int* __restrict__ cursor) {
  __shared__ unsigned int buf[1024];
  __shared__ unsigned int carry;
  int t = threadIdx.x;
  if (t == 0) carry = 0;
  __syncthreads();
  for (int base = 0; base < NBUCKET; base += 1024) {
    int i = base + t;
    unsigned int v = (i < NBUCKET) ? counts[i] : 0u;
    buf[t] = v;
    __syncthreads();
    for (int d = 1; d < 1024; d <<= 1) {
      unsigned int add = (t >= d) ? buf[t - d] : 0u;
      __syncthreads();
      buf[t] += add;
      __syncthreads();
    }
    unsigned int excl = buf[t] - v + carry;
    if (i < NBUCKET) { ofs[i] = excl; cursor[i] = excl; }
    __syncthreads();
    if (t == 1023) carry += buf[1023];
    __syncthreads();
  }
  if (t == 0) ofs[NBUCKET] = carry;
}

// pack: src(16b) | rel_local(3b)<<16 | dst_local(4b)<<19
__global__ void scatter_kernel(const int* __restrict__ src, const int* __restrict__ dst,
                               const int* __restrict__ et,
                               unsigned int* __restrict__ cursor,
                               unsigned int* __restrict__ epk, int n) {
  int i = blockIdx.x * 256 + threadIdx.x;
  if (i < n) {
    int d = dst[i], e = et[i];
    int b = (d >> 4) * 4 + (e / 5);
    unsigned int pos = atomicAdd(&cursor[b], 1u);
    epk[pos] = (unsigned int)src[i] | ((unsigned int)(e % 5) << 16)
             | ((unsigned int)(d & 15) << 19);
  }
}

// ---------------- fused RGCN layer ----------------
// 3125 blocks x 256 threads (4 waves). LDS ~64 KB -> 2 blocks/CU.
__global__ __launch_bounds__(256) void rgcn_layer_kernel(
    const unsigned short* __restrict__ hb,    // [N,128] bf16
    const unsigned short* __restrict__ WP,    // packed weights
    const float* __restrict__ bias,           // [128] this layer
    int layer,
    const unsigned int* __restrict__ bofs,    // [NBUCKET+1]
    const unsigned int* __restrict__ epk,     // [E] packed, bucket-sorted
    float* __restrict__ out)                  // [N,128] fp32
{
  __shared__ __align__(16) float S[TILE][STR_D];             // 51968 B
  __shared__ __align__(16) unsigned short stage[4][3][512];  // 12288 B: wave x slot x 4 rows
  __shared__ unsigned int bofs_l[5];

  const int tid  = threadIdx.x;
  const int lane = tid & 63;
  const int w    = tid >> 6;        // wave 0..3
  const int quad = lane >> 4;
  const int m    = lane & 15;
  const int dst_base = blockIdx.x * TILE;

  if (tid < 5) bofs_l[tid] = bofs[blockIdx.x * 4 + tid];

  f32x4 acc[8];
#pragma unroll
  for (int nc = 0; nc < 8; ++nc) acc[nc] = (f32x4){0.f, 0.f, 0.f, 0.f};

  for (int c = 0; c < 4; ++c) {
    const int rbase = c * 5;
    const int rc = (c == 3) ? 6 : 5;

    // zero atomic-target slots 0..4
    for (int t = tid; t < TILE * 5 * 32; t += 256) {
      int d = t / 160, rem = t - d * 160;
      int rl = rem >> 5, kq = rem & 31;
      *(float4*)&S[d][rl * STR_R + kq * 4] = (float4){0.f, 0.f, 0.f, 0.f};
    }
    // self-loop rows into slot 5 (chunk 3 only)
    if (c == 3) {
      int d = tid >> 4, mm = tid & 15;
      short8 hv = *(const short8*)(hb + (size_t)(dst_base + d) * DIM + mm * 8);
      float4 f0, f1;
      f0.x = bf16_raw_to_f32((unsigned short)hv[0]);
      f0.y = bf16_raw_to_f32((unsigned short)hv[1]);
      f0.z = bf16_raw_to_f32((unsigned short)hv[2]);
      f0.w = bf16_raw_to_f32((unsigned short)hv[3]);
      f1.x = bf16_raw_to_f32((unsigned short)hv[4]);
      f1.y = bf16_raw_to_f32((unsigned short)hv[5]);
      f1.z = bf16_raw_to_f32((unsigned short)hv[6]);
      f1.w = bf16_raw_to_f32((unsigned short)hv[7]);
      *(float4*)&S[d][5 * STR_R + mm * 8]     = f0;
      *(float4*)&S[d][5 * STR_R + mm * 8 + 4] = f1;
    }
    __syncthreads();

    // phase 1: per wave, 48-edge passes; rounds of 12 DMA'd rows (3 slots x 4).
    {
      const int cbeg = (int)bofs_l[c], cend = (int)bofs_l[c + 1];
      for (int base = cbeg + w * 48; base < cend; base += 192) {
        const int rem = cend - base;             // wave-uniform
        unsigned int pk_my = 0xFFFFFFFFu;
        {
          int idx = base + lane;
          if (lane < 48 && idx < cend) pk_my = epk[idx];
        }
#pragma unroll
        for (int r = 0; r < 4; ++r) {
          if (r * 12 >= rem) break;
          // issue: 3 slots x 4 rows, per-lane divergent gptr, uniform LDS base
#pragma unroll
          for (int ss = 0; ss < 3; ++ss) {
            if (r * 12 + ss * 4 >= rem) break;
            unsigned int pk_s =
                (unsigned int)__shfl((int)pk_my, r * 12 + ss * 4 + quad, 64);
            int src = (int)(pk_s & 0xffffu);     // sentinel -> row 65535 (in ws, unused)
            const unsigned short* gp = hb + (size_t)src * DIM + m * 8;
            __builtin_amdgcn_global_load_lds((gas_u32p)gp, (las_u32p)&stage[w][ss][0],
                                             16, 0, 0);
          }
          __builtin_amdgcn_s_waitcnt(0x0f70);    // vmcnt(0), ignore lgkm/exp
          // drain: cvt + 8 bank-rotated LDS atomics per row
#pragma unroll
          for (int ss = 0; ss < 3; ++ss) {
            if (r * 12 + ss * 4 >= rem) break;
            unsigned int pk_s =
                (unsigned int)__shfl((int)pk_my, r * 12 + ss * 4 + quad, 64);
            if (pk_s != 0xFFFFFFFFu) {
              short8 hv = *(const short8*)&stage[w][ss][quad * 128 + m * 8];
              int rl = (int)((pk_s >> 16) & 7u);
              int d  = (int)((pk_s >> 19) & 15u);
              float* bb = &S[d][rl * STR_R + m * 8];
#pragma unroll
              for (int jj = 0; jj < 8; ++jj) {
                int j = (jj + m) & 7;
                atomicAdd(bb + j, bf16_raw_to_f32((unsigned short)hv[j]));
              }
            }
          }
        }
      }
    }
    __syncthreads();

    // phase 2: K-split. wave w owns k in [32w, 32w+32); A-frag reused for 8 nc.
    for (int rl = 0; rl < rc; ++rl) {
      const int r = rbase + rl;
      const float* ap = &S[m][rl * STR_R + w * 32 + quad * 8];
      float4 f0 = *(const float4*)ap;
      float4 f1 = *(const float4*)(ap + 4);
      short8 a;
      a[0] = (short)f32_to_bf16_raw(f0.x);
      a[1] = (short)f32_to_bf16_raw(f0.y);
      a[2] = (short)f32_to_bf16_raw(f0.z);
      a[3] = (short)f32_to_bf16_raw(f0.w);
      a[4] = (short)f32_to_bf16_raw(f1.x);
      a[5] = (short)f32_to_bf16_raw(f1.y);
      a[6] = (short)f32_to_bf16_raw(f1.z);
      a[7] = (short)f32_to_bf16_raw(f1.w);
      const unsigned short* bp =
          WP + ((((size_t)(layer * NRELP + r) * 4 + w) * 8) * 64 + lane) * 8;
#pragma unroll
      for (int nc = 0; nc < 8; ++nc) {
        short8 b = *(const short8*)(bp + (size_t)nc * 64 * 8);
        acc[nc] = __builtin_amdgcn_mfma_f32_16x16x32_bf16(a, b, acc[nc], 0, 0, 0);
      }
    }
    __syncthreads();
  }

  // cross-wave K-reduction through LDS. red[w][row16][132] (reuse S region)
  float* red = &S[0][0];
#pragma unroll
  for (int nc = 0; nc < 8; ++nc)
#pragma unroll
    for (int i = 0; i < 4; ++i)
      red[w * (16 * 132) + (quad * 4 + i) * 132 + nc * 16 + m] = acc[nc][i];
  __syncthreads();

  {
    int row = tid >> 4, cb = (tid & 15) * 8;
    float4 b0 = *(const float4*)(bias + cb);
    float4 b1 = *(const float4*)(bias + cb + 4);
    float o[8];
#pragma unroll
    for (int j = 0; j < 8; ++j) {
      int col = cb + j;
      o[j] = red[0 * 2112 + row * 132 + col] + red[1 * 2112 + row * 132 + col]
           + red[2 * 2112 + row * 132 + col] + red[3 * 2112 + row * 132 + col];
    }
    o[0] += b0.x; o[1] += b0.y; o[2] += b0.z; o[3] += b0.w;
    o[4] += b1.x; o[5] += b1.y; o[6] += b1.z; o[7] += b1.w;
    float* op = out + (size_t)(dst_base + row) * DIM + cb;
    *(float4*)op       = (float4){o[0], o[1], o[2], o[3]};
    *(float4*)(op + 4) = (float4){o[4], o[5], o[6], o[7]};
  }
}

// ---------------- launch ----------------
extern "C" void kernel_launch(void* const* d_in, const int* in_sizes, int n_in,
                              void* d_out, int out_size, void* d_ws, size_t ws_size,
                              hipStream_t stream) {
  const float* h0     = (const float*)d_in[0];
  const float* W      = (const float*)d_in[1];
  const float* loop_w = (const float*)d_in[2];
  const float* bias   = (const float*)d_in[3];
  const int* esrc     = (const int*)d_in[4];
  const int* edst     = (const int*)d_in[5];
  const int* etyp     = (const int*)d_in[6];
  float* out = (float*)d_out;

  char* ws = (char*)d_ws;
  size_t off = 0;
  auto alloc = [&](size_t bytes) -> void* {
    void* p = ws + off;
    off = (off + bytes + 255) & ~(size_t)255;
    return p;
  };
  unsigned short* h_bf16 = (unsigned short*)alloc((size_t)NN * DIM * 2);
  unsigned short* WP     = (unsigned short*)alloc((size_t)PACKED_ELEMS * 2);
  float*          h1     = (float*)alloc((size_t)NN * DIM * 4);
  unsigned int*   counts = (unsigned int*)alloc((size_t)NBUCKET * 4);
  unsigned int*   bofs   = (unsigned int*)alloc((size_t)(NBUCKET + 1) * 4);
  unsigned int*   cursor = (unsigned int*)alloc((size_t)NBUCKET * 4);
  unsigned int*   epk    = (unsigned int*)alloc((size_t)NE * 4);

  (void)hipMemsetAsync(counts, 0, (size_t)NBUCKET * 4, stream);
  hist_kernel<<<NE / 256, 256, 0, stream>>>(edst, etyp, counts, NE);
  scan_kernel<<<1, 1024, 0, stream>>>(counts, bofs, cursor);
  scatter_kernel<<<NE / 256, 256, 0, stream>>>(esrc, edst, etyp, cursor, epk, NE);

  pack_w_kernel<<<(PACKED_ELEMS + 255) / 256, 256, 0, stream>>>(W, loop_w, WP);

  cvt_bf16_kernel<<<(NN * DIM / 4 + 255) / 256, 256, 0, stream>>>(h0, h_bf16, NN * DIM / 4);
  rgcn_layer_kernel<<<NTILE, 256, 0, stream>>>(h_bf16, WP, bias, 0, bofs, epk, h1);

  cvt_bf16_kernel<<<(NN * DIM / 4 + 255) / 256, 256, 0, stream>>>(h1, h_bf16, NN * DIM / 4);
  rgcn_layer_kernel<<<NTILE, 256, 0, stream>>>(h_bf16, WP, bias + DIM, 1, bofs, epk, out);
}

// Round 6
// 755.917 us; speedup vs baseline: 3.7478x; 3.4823x over previous
//
#include <hip/hip_runtime.h>
#include <hip/hip_bf16.h>
#include <stdint.h>

// GNN_758: stacked RelGraphConv x2.  N=50000, E=1.6M, D=128, R=20.
// agg[dst] = sum_r (sum_{e in rel r -> dst} h[src]) @ W[r]; self-loop = rel 20.
// R6: NO LDS atomics in the hot path. Per chunk: in-LDS counting sort of ~128
// edges into (dst_local, rel) cells (2 lane-RMWs/edge), then each 16-lane group
// exclusively owns one dst row and register-accumulates its cells, flushing with
// plain ds_write_b128. Phase 2 (K-split MFMA) and epilogue unchanged.

#define NN 50000
#define NE 1600000
#define DIM 128
#define NREL 20
#define NRELP 21
#define TILE 16
#define NTILE (NN / TILE)        // 3125
#define NBUCKET (NTILE * 4)      // 12500 (tile, rel-chunk)
#define STR_R 130                // rel slot stride in floats
#define STR_D 781                // per-dst stride (odd -> clean banks)
#define SPK_CAP 320              // max edges per (tile,chunk) bucket (mean 128)
#define PACKED_ELEMS (2 * NRELP * 4 * 8 * 64 * 8)   // 688128

typedef __attribute__((ext_vector_type(8))) short short8;
typedef __attribute__((ext_vector_type(4))) float f32x4;

__device__ __forceinline__ unsigned short f32_to_bf16_raw(float f) {
  union { float f; unsigned u; } c; c.f = f;
  unsigned u = c.u;
  return (unsigned short)((u + 0x7fffu + ((u >> 16) & 1u)) >> 16);  // RNE
}
__device__ __forceinline__ float bf16_raw_to_f32(unsigned short s) {
  union { unsigned u; float f; } c; c.u = ((unsigned)s) << 16;
  return c.f;
}

// ---------------- fp32 -> bf16 (x4), nontemporal stores ----------------
__global__ void cvt_bf16_kernel(const float* __restrict__ in,
                                unsigned short* __restrict__ out, int n4) {
  int i = blockIdx.x * 256 + threadIdx.x;
  if (i < n4) {
    float4 f = ((const float4*)in)[i];
    unsigned long long p =
        (unsigned long long)f32_to_bf16_raw(f.x)
      | ((unsigned long long)f32_to_bf16_raw(f.y) << 16)
      | ((unsigned long long)f32_to_bf16_raw(f.z) << 32)
      | ((unsigned long long)f32_to_bf16_raw(f.w) << 48);
    __builtin_nontemporal_store(p, (unsigned long long*)out + i);  // clean -> L3
  }
}

// ---------------- pack W (+loop_w as rel 20) into B-fragment order ----------------
// WP flat: ((((l*21 + r)*4 + ks)*8 + nc)*64 + lane)*8 + j  (verified R0/R1)
__global__ void pack_w_kernel(const float* __restrict__ W,
                              const float* __restrict__ loop_w,
                              unsigned short* __restrict__ WP) {
  int idx = blockIdx.x * 256 + threadIdx.x;
  if (idx >= PACKED_ELEMS) return;
  int j = idx & 7;       int t = idx >> 3;
  int lane = t & 63;     t >>= 6;
  int nc = t & 7;        t >>= 3;
  int ks = t & 3;        t >>= 2;
  int r = t % NRELP;     int l = t / NRELP;
  int k = ks * 32 + (lane >> 4) * 8 + j;
  int n = nc * 16 + (lane & 15);
  float v = (r < NREL) ? W[(((size_t)l * NREL + r) * DIM + k) * DIM + n]
                       : loop_w[((size_t)l * DIM + k) * DIM + n];
  WP[idx] = f32_to_bf16_raw(v);
}

// ---------------- edge bucketing by (dst_tile, rel_chunk) ----------------
__global__ void hist_kernel(const int* __restrict__ dst, const int* __restrict__ et,
                            unsigned int* __restrict__ counts, int n) {
  int i = blockIdx.x * 256 + threadIdx.x;
  if (i < n) {
    int b = (dst[i] >> 4) * 4 + (et[i] / 5);
    atomicAdd(&counts[b], 1u);
  }
}

__global__ void scan_kernel(const unsigned int* __restrict__ counts,
                            unsigned int* __restrict__ ofs,
                            unsigned int* __restrict__ cursor) {
  __shared__ unsigned int buf[1024];
  __shared__ unsigned int carry;
  int t = threadIdx.x;
  if (t == 0) carry = 0;
  __syncthreads();
  for (int base = 0; base < NBUCKET; base += 1024) {
    int i = base + t;
    unsigned int v = (i < NBUCKET) ? counts[i] : 0u;
    buf[t] = v;
    __syncthreads();
    for (int d = 1; d < 1024; d <<= 1) {
      unsigned int add = (t >= d) ? buf[t - d] : 0u;
      __syncthreads();
      buf[t] += add;
      __syncthreads();
    }
    unsigned int excl = buf[t] - v + carry;
    if (i < NBUCKET) { ofs[i] = excl; cursor[i] = excl; }
    __syncthreads();
    if (t == 1023) carry += buf[1023];
    __syncthreads();
  }
  if (t == 0) ofs[NBUCKET] = carry;
}

// pack: src(16b) | rel_local(3b)<<16 | dst_local(4b)<<19
__global__ void scatter_kernel(const int* __restrict__ src, const int* __restrict__ dst,
                               const int* __restrict__ et,
                               unsigned int* __restrict__ cursor,
                               unsigned int* __restrict__ epk, int n) {
  int i = blockIdx.x * 256 + threadIdx.x;
  if (i < n) {
    int d = dst[i], e = et[i];
    int b = (d >> 4) * 4 + (e / 5);
    unsigned int pos = atomicAdd(&cursor[b], 1u);
    epk[pos] = (unsigned int)src[i] | ((unsigned int)(e % 5) << 16)
             | ((unsigned int)(d & 15) << 19);
  }
}

// ---------------- fused RGCN layer ----------------
// 3125 blocks x 256 threads (4 waves). LDS ~54 KB -> 3 blocks/CU.
__global__ __launch_bounds__(256) void rgcn_layer_kernel(
    const unsigned short* __restrict__ hb,    // [N,128] bf16
    const unsigned short* __restrict__ WP,    // packed weights
    const float* __restrict__ bias,           // [128] this layer
    int layer,
    const unsigned int* __restrict__ bofs,    // [NBUCKET+1]
    const unsigned int* __restrict__ epk,     // [E] packed, bucket-sorted
    float* __restrict__ out)                  // [N,128] fp32
{
  __shared__ __align__(16) float S[TILE][STR_D];   // 49984 B
  __shared__ unsigned int hist_s[128];             // (d<<3)|rl cell counts
  __shared__ unsigned int ofs_s[128];              // exclusive offsets
  __shared__ unsigned int cur_s[128];              // scatter cursors (also scan buf)
  __shared__ unsigned int spk[SPK_CAP];            // cell-sorted packed edges
  __shared__ unsigned int bofs_l[5];

  const int tid  = threadIdx.x;
  const int lane = tid & 63;
  const int w    = tid >> 6;        // wave 0..3
  const int quad = lane >> 4;
  const int m    = lane & 15;
  const int g    = w * 4 + quad;    // 16-lane group id == owned dst_local
  const int dst_base = blockIdx.x * TILE;

  if (tid < 5) bofs_l[tid] = bofs[blockIdx.x * 4 + tid];

  f32x4 acc[8];
#pragma unroll
  for (int nc = 0; nc < 8; ++nc) acc[nc] = (f32x4){0.f, 0.f, 0.f, 0.f};

  for (int c = 0; c < 4; ++c) {
    const int rbase = c * 5;
    const int rc = (c == 3) ? 6 : 5;

    // ---- in-LDS counting sort of this chunk's edges into (d,rl) cells ----
    if (tid < 128) hist_s[tid] = 0u;
    __syncthreads();
    const int cbeg = (int)bofs_l[c], cend = (int)bofs_l[c + 1];
    for (int i = cbeg + tid; i < cend; i += 256)
      atomicAdd(&hist_s[(epk[i] >> 16) & 127u], 1u);
    __syncthreads();
    // Hillis-Steele inclusive scan over 128 cells (in cur_s)
    if (tid < 128) cur_s[tid] = hist_s[tid];
    __syncthreads();
    for (int d2 = 1; d2 < 128; d2 <<= 1) {
      unsigned int v = 0;
      if (tid < 128 && tid >= d2) v = cur_s[tid - d2];
      __syncthreads();
      if (tid < 128) cur_s[tid] += v;
      __syncthreads();
    }
    if (tid < 128) {
      unsigned int e = cur_s[tid] - hist_s[tid];   // exclusive
      ofs_s[tid] = e;
      cur_s[tid] = e;
    }
    __syncthreads();
    for (int i = cbeg + tid; i < cend; i += 256) {
      unsigned int pk = epk[i];
      unsigned int pos = atomicAdd(&cur_s[(pk >> 16) & 127u], 1u);
      if (pos < SPK_CAP) spk[pos] = pk;
    }
    __syncthreads();

    // ---- phase 1: group g owns dst g; register-accumulate each cell ----
    for (int rl = 0; rl < rc; ++rl) {
      float a0 = 0.f, a1 = 0.f, a2 = 0.f, a3 = 0.f;
      float a4 = 0.f, a5 = 0.f, a6 = 0.f, a7 = 0.f;
      if (rl < 5) {
        const int cell = (g << 3) | rl;
        const int cnt = (int)hist_s[cell];
        const int beg = (int)ofs_s[cell];
        for (int i = 0; i < cnt; ++i) {
          unsigned int pk = spk[beg + i];
          short8 hv = *(const short8*)(hb + (size_t)(pk & 0xffffu) * DIM + m * 8);
          a0 += bf16_raw_to_f32((unsigned short)hv[0]);
          a1 += bf16_raw_to_f32((unsigned short)hv[1]);
          a2 += bf16_raw_to_f32((unsigned short)hv[2]);
          a3 += bf16_raw_to_f32((unsigned short)hv[3]);
          a4 += bf16_raw_to_f32((unsigned short)hv[4]);
          a5 += bf16_raw_to_f32((unsigned short)hv[5]);
          a6 += bf16_raw_to_f32((unsigned short)hv[6]);
          a7 += bf16_raw_to_f32((unsigned short)hv[7]);
        }
      } else {
        // self-loop (chunk 3, slot 5): own row
        short8 hv = *(const short8*)(hb + (size_t)(dst_base + g) * DIM + m * 8);
        a0 = bf16_raw_to_f32((unsigned short)hv[0]);
        a1 = bf16_raw_to_f32((unsigned short)hv[1]);
        a2 = bf16_raw_to_f32((unsigned short)hv[2]);
        a3 = bf16_raw_to_f32((unsigned short)hv[3]);
        a4 = bf16_raw_to_f32((unsigned short)hv[4]);
        a5 = bf16_raw_to_f32((unsigned short)hv[5]);
        a6 = bf16_raw_to_f32((unsigned short)hv[6]);
        a7 = bf16_raw_to_f32((unsigned short)hv[7]);
      }
      *(float4*)&S[g][rl * STR_R + m * 8]     = (float4){a0, a1, a2, a3};
      *(float4*)&S[g][rl * STR_R + m * 8 + 4] = (float4){a4, a5, a6, a7};
    }
    __syncthreads();

    // ---- phase 2: K-split. wave w owns k in [32w, 32w+32); A reused for 8 nc ----
    for (int rl = 0; rl < rc; ++rl) {
      const int r = rbase + rl;
      const float* ap = &S[m][rl * STR_R + w * 32 + quad * 8];
      float4 f0 = *(const float4*)ap;
      float4 f1 = *(const float4*)(ap + 4);
      short8 a;
      a[0] = (short)f32_to_bf16_raw(f0.x);
      a[1] = (short)f32_to_bf16_raw(f0.y);
      a[2] = (short)f32_to_bf16_raw(f0.z);
      a[3] = (short)f32_to_bf16_raw(f0.w);
      a[4] = (short)f32_to_bf16_raw(f1.x);
      a[5] = (short)f32_to_bf16_raw(f1.y);
      a[6] = (short)f32_to_bf16_raw(f1.z);
      a[7] = (short)f32_to_bf16_raw(f1.w);
      const unsigned short* bp =
          WP + ((((size_t)(layer * NRELP + r) * 4 + w) * 8) * 64 + lane) * 8;
#pragma unroll
      for (int nc = 0; nc < 8; ++nc) {
        short8 b = *(const short8*)(bp + (size_t)nc * 64 * 8);
        acc[nc] = __builtin_amdgcn_mfma_f32_16x16x32_bf16(a, b, acc[nc], 0, 0, 0);
      }
    }
    __syncthreads();
  }

  // cross-wave K-reduction through LDS. red[w][row16][132] (reuse S region)
  float* red = &S[0][0];
#pragma unroll
  for (int nc = 0; nc < 8; ++nc)
#pragma unroll
    for (int i = 0; i < 4; ++i)
      red[w * (16 * 132) + (quad * 4 + i) * 132 + nc * 16 + m] = acc[nc][i];
  __syncthreads();

  {
    int row = tid >> 4, cb = (tid & 15) * 8;
    float4 b0 = *(const float4*)(bias + cb);
    float4 b1 = *(const float4*)(bias + cb + 4);
    float o[8];
#pragma unroll
    for (int j = 0; j < 8; ++j) {
      int col = cb + j;
      o[j] = red[0 * 2112 + row * 132 + col] + red[1 * 2112 + row * 132 + col]
           + red[2 * 2112 + row * 132 + col] + red[3 * 2112 + row * 132 + col];
    }
    o[0] += b0.x; o[1] += b0.y; o[2] += b0.z; o[3] += b0.w;
    o[4] += b1.x; o[5] += b1.y; o[6] += b1.z; o[7] += b1.w;
    float* op = out + (size_t)(dst_base + row) * DIM + cb;
    *(float4*)op       = (float4){o[0], o[1], o[2], o[3]};
    *(float4*)(op + 4) = (float4){o[4], o[5], o[6], o[7]};
  }
}

// ---------------- launch ----------------
extern "C" void kernel_launch(void* const* d_in, const int* in_sizes, int n_in,
                              void* d_out, int out_size, void* d_ws, size_t ws_size,
                              hipStream_t stream) {
  const float* h0     = (const float*)d_in[0];
  const float* W      = (const float*)d_in[1];
  const float* loop_w = (const float*)d_in[2];
  const float* bias   = (const float*)d_in[3];
  const int* esrc     = (const int*)d_in[4];
  const int* edst     = (const int*)d_in[5];
  const int* etyp     = (const int*)d_in[6];
  float* out = (float*)d_out;

  char* ws = (char*)d_ws;
  size_t off = 0;
  auto alloc = [&](size_t bytes) -> void* {
    void* p = ws + off;
    off = (off + bytes + 255) & ~(size_t)255;
    return p;
  };
  unsigned short* h_bf16 = (unsigned short*)alloc((size_t)NN * DIM * 2);
  unsigned short* WP     = (unsigned short*)alloc((size_t)PACKED_ELEMS * 2);
  float*          h1     = (float*)alloc((size_t)NN * DIM * 4);
  unsigned int*   counts = (unsigned int*)alloc((size_t)NBUCKET * 4);
  unsigned int*   bofs   = (unsigned int*)alloc((size_t)(NBUCKET + 1) * 4);
  unsigned int*   cursor = (unsigned int*)alloc((size_t)NBUCKET * 4);
  unsigned int*   epk    = (unsigned int*)alloc((size_t)NE * 4);

  (void)hipMemsetAsync(counts, 0, (size_t)NBUCKET * 4, stream);
  hist_kernel<<<NE / 256, 256, 0, stream>>>(edst, etyp, counts, NE);
  scan_kernel<<<1, 1024, 0, stream>>>(counts, bofs, cursor);
  scatter_kernel<<<NE / 256, 256, 0, stream>>>(esrc, edst, etyp, cursor, epk, NE);

  pack_w_kernel<<<(PACKED_ELEMS + 255) / 256, 256, 0, stream>>>(W, loop_w, WP);

  cvt_bf16_kernel<<<(NN * DIM / 4 + 255) / 256, 256, 0, stream>>>(h0, h_bf16, NN * DIM / 4);
  rgcn_layer_kernel<<<NTILE, 256, 0, stream>>>(h_bf16, WP, bias, 0, bofs, epk, h1);

  cvt_bf16_kernel<<<(NN * DIM / 4 + 255) / 256, 256, 0, stream>>>(h1, h_bf16, NN * DIM / 4);
  rgcn_layer_kernel<<<NTILE, 256, 0, stream>>>(h_bf16, WP, bias + DIM, 1, bofs, epk, out);
}

// Round 7
// 742.221 us; speedup vs baseline: 3.8169x; 1.0185x over previous
//
#include <hip/hip_runtime.h>
#include <hip/hip_bf16.h>
#include <stdint.h>

// GNN_758: stacked RelGraphConv x2.  N=50000, E=1.6M, D=128, R=20.
// agg[dst] = sum_r (sum_{e in rel r -> dst} h[src]) @ W[r]; self-loop = rel 20.
// R7: edges globally sorted by cell (dst*32 + chunk*8 + rl) in preprocessing
// (hist -> 3-kernel scan -> scatter, u16 src payload). rgcn has NO in-kernel
// sort: per-cell offsets from a 513-word coalesced load, block's srcs staged
// once into LDS. Layer 0 writes bf16 directly (no fp32 h1, no second cvt).

#define NN 50000
#define NE 1600000
#define DIM 128
#define NREL 20
#define NRELP 21
#define TILE 16
#define NTILE (NN / TILE)          // 3125
#define CELLS (NN * 32)            // dst*32 + chunk*8 + rl (rl 0..4 used)
#define SCAN_EPB 2048
#define NBLK_A ((CELLS + SCAN_EPB - 1) / SCAN_EPB)   // 782
#define STR_R 130                  // rel slot stride in floats
#define STR_D 781                  // per-dst stride (odd -> clean banks)
#define SPK_CAP 768                // staged srcs per block (mean 512, +11 sd)
#define PACKED_ELEMS (2 * NRELP * 4 * 8 * 64 * 8)   // 688128

typedef __attribute__((ext_vector_type(8))) short short8;
typedef __attribute__((ext_vector_type(4))) float f32x4;

__device__ __forceinline__ unsigned short f32_to_bf16_raw(float f) {
  union { float f; unsigned u; } c; c.f = f;
  unsigned u = c.u;
  return (unsigned short)((u + 0x7fffu + ((u >> 16) & 1u)) >> 16);  // RNE
}
__device__ __forceinline__ float bf16_raw_to_f32(unsigned short s) {
  union { unsigned u; float f; } c; c.u = ((unsigned)s) << 16;
  return c.f;
}

// ---------------- fp32 -> bf16 (x4), nontemporal stores ----------------
__global__ void cvt_bf16_kernel(const float* __restrict__ in,
                                unsigned short* __restrict__ out, int n4) {
  int i = blockIdx.x * 256 + threadIdx.x;
  if (i < n4) {
    float4 f = ((const float4*)in)[i];
    unsigned long long p =
        (unsigned long long)f32_to_bf16_raw(f.x)
      | ((unsigned long long)f32_to_bf16_raw(f.y) << 16)
      | ((unsigned long long)f32_to_bf16_raw(f.z) << 32)
      | ((unsigned long long)f32_to_bf16_raw(f.w) << 48);
    __builtin_nontemporal_store(p, (unsigned long long*)out + i);  // clean -> L3
  }
}

// ---------------- pack W (+loop_w as rel 20) into B-fragment order ----------------
// WP flat: ((((l*21 + r)*4 + ks)*8 + nc)*64 + lane)*8 + j  (verified R0/R1)
__global__ void pack_w_kernel(const float* __restrict__ W,
                              const float* __restrict__ loop_w,
                              unsigned short* __restrict__ WP) {
  int idx = blockIdx.x * 256 + threadIdx.x;
  if (idx >= PACKED_ELEMS) return;
  int j = idx & 7;       int t = idx >> 3;
  int lane = t & 63;     t >>= 6;
  int nc = t & 7;        t >>= 3;
  int ks = t & 3;        t >>= 2;
  int r = t % NRELP;     int l = t / NRELP;
  int k = ks * 32 + (lane >> 4) * 8 + j;
  int n = nc * 16 + (lane & 15);
  float v = (r < NREL) ? W[(((size_t)l * NREL + r) * DIM + k) * DIM + n]
                       : loop_w[((size_t)l * DIM + k) * DIM + n];
  WP[idx] = f32_to_bf16_raw(v);
}

// ---------------- global cell sort: hist -> scan(A,B,C) -> scatter ----------------
__global__ void hist_kernel(const int* __restrict__ dst, const int* __restrict__ et,
                            unsigned int* __restrict__ cnt, int n) {
  int i = blockIdx.x * 256 + threadIdx.x;
  if (i < n) {
    int e = et[i];
    atomicAdd(&cnt[dst[i] * 32 + (e / 5) * 8 + (e % 5)], 1u);
  }
}

__global__ void scanA_kernel(const unsigned int* __restrict__ cnt,
                             unsigned int* __restrict__ cofs,
                             unsigned int* __restrict__ btot) {
  __shared__ unsigned int buf[256];
  int tid = threadIdx.x;
  int base = blockIdx.x * SCAN_EPB + tid * 8;
  unsigned int v[8], p[8], s = 0;
#pragma unroll
  for (int j = 0; j < 8; ++j) {
    v[j] = (base + j < CELLS) ? cnt[base + j] : 0u;
    p[j] = s; s += v[j];
  }
  buf[tid] = s;
  __syncthreads();
  for (int d = 1; d < 256; d <<= 1) {
    unsigned int a = (tid >= d) ? buf[tid - d] : 0u;
    __syncthreads();
    buf[tid] += a;
    __syncthreads();
  }
  unsigned int excl = buf[tid] - s;
#pragma unroll
  for (int j = 0; j < 8; ++j)
    if (base + j < CELLS) cofs[base + j] = excl + p[j];
  if (tid == 255) btot[blockIdx.x] = buf[255];
}

__global__ void scanB_kernel(unsigned int* __restrict__ btot,
                             unsigned int* __restrict__ cofs) {
  __shared__ unsigned int buf[1024];
  int t = threadIdx.x;
  unsigned int v = (t < NBLK_A) ? btot[t] : 0u;
  buf[t] = v;
  __syncthreads();
  for (int d = 1; d < 1024; d <<= 1) {
    unsigned int a = (t >= d) ? buf[t - d] : 0u;
    __syncthreads();
    buf[t] += a;
    __syncthreads();
  }
  if (t < NBLK_A) btot[t] = buf[t] - v;   // exclusive
  if (t == 1023) cofs[CELLS] = buf[1023]; // = NE sentinel
}

__global__ void scanC_kernel(const unsigned int* __restrict__ btot,
                             unsigned int* __restrict__ cofs,
                             unsigned int* __restrict__ cursor) {
  int base = blockIdx.x * SCAN_EPB + threadIdx.x * 8;
  unsigned int add = btot[blockIdx.x];
#pragma unroll
  for (int j = 0; j < 8; ++j)
    if (base + j < CELLS) {
      unsigned int x = cofs[base + j] + add;
      cofs[base + j] = x;
      cursor[base + j] = x;
    }
}

__global__ void scatter_kernel(const int* __restrict__ src, const int* __restrict__ dst,
                               const int* __restrict__ et,
                               unsigned int* __restrict__ cursor,
                               unsigned short* __restrict__ es, int n) {
  int i = blockIdx.x * 256 + threadIdx.x;
  if (i < n) {
    int e = et[i];
    unsigned int pos = atomicAdd(&cursor[dst[i] * 32 + (e / 5) * 8 + (e % 5)], 1u);
    es[pos] = (unsigned short)src[i];   // N < 65536
  }
}

// ---------------- fused RGCN layer ----------------
// 3125 blocks x 256 threads (4 waves). LDS ~53.5 KB -> 3 blocks/CU.
__global__ __launch_bounds__(256) void rgcn_layer_kernel(
    const unsigned short* __restrict__ hb,    // [N,128] bf16
    const unsigned short* __restrict__ WP,    // packed weights
    const float* __restrict__ bias,           // [128] this layer
    int layer,
    const unsigned int* __restrict__ cofs,    // [CELLS+1] cell offsets
    const unsigned short* __restrict__ es,    // [E] srcs, cell-sorted
    float* __restrict__ outf,                 // fp32 out (layer 1) or null
    unsigned short* __restrict__ outb)        // bf16 out (layer 0) or null
{
  __shared__ __align__(16) float S[TILE][STR_D];   // 49984 B
  __shared__ unsigned int cofs_l[513];             // local cell offsets
  __shared__ unsigned short spk[SPK_CAP];          // staged srcs

  const int tid  = threadIdx.x;
  const int lane = tid & 63;
  const int w    = tid >> 6;        // wave 0..3
  const int quad = lane >> 4;
  const int m    = lane & 15;
  const int g    = w * 4 + quad;    // 16-lane group id == owned dst_local
  const int dst_base = blockIdx.x * TILE;

  for (int i = tid; i < 513; i += 256) cofs_l[i] = cofs[blockIdx.x * 512 + i];
  __syncthreads();
  const int e0 = (int)cofs_l[0];
  const int etot = (int)cofs_l[512] - e0;
  for (int i = tid; i < etot && i < SPK_CAP; i += 256) spk[i] = es[e0 + i];
  __syncthreads();

  f32x4 acc[8];
#pragma unroll
  for (int nc = 0; nc < 8; ++nc) acc[nc] = (f32x4){0.f, 0.f, 0.f, 0.f};

  for (int c = 0; c < 4; ++c) {
    const int rbase = c * 5;
    const int rc = (c == 3) ? 6 : 5;

    // ---- phase 1: group g owns dst g; register-accumulate each cell ----
    for (int rl = 0; rl < rc; ++rl) {
      float a0 = 0.f, a1 = 0.f, a2 = 0.f, a3 = 0.f;
      float a4 = 0.f, a5 = 0.f, a6 = 0.f, a7 = 0.f;
      if (rl < 5) {
        const int idx = g * 32 + c * 8 + rl;
        const int beg = (int)cofs_l[idx] - e0;
        const int end = (int)cofs_l[idx + 1] - e0;
        const bool lds_ok = (end <= SPK_CAP);
        for (int i = beg; i < end; ++i) {
          int src = lds_ok ? (int)spk[i] : (int)es[e0 + i];
          short8 hv = *(const short8*)(hb + (size_t)src * DIM + m * 8);
          a0 += bf16_raw_to_f32((unsigned short)hv[0]);
          a1 += bf16_raw_to_f32((unsigned short)hv[1]);
          a2 += bf16_raw_to_f32((unsigned short)hv[2]);
          a3 += bf16_raw_to_f32((unsigned short)hv[3]);
          a4 += bf16_raw_to_f32((unsigned short)hv[4]);
          a5 += bf16_raw_to_f32((unsigned short)hv[5]);
          a6 += bf16_raw_to_f32((unsigned short)hv[6]);
          a7 += bf16_raw_to_f32((unsigned short)hv[7]);
        }
      } else {
        // self-loop (chunk 3, slot 5): own row
        short8 hv = *(const short8*)(hb + (size_t)(dst_base + g) * DIM + m * 8);
        a0 = bf16_raw_to_f32((unsigned short)hv[0]);
        a1 = bf16_raw_to_f32((unsigned short)hv[1]);
        a2 = bf16_raw_to_f32((unsigned short)hv[2]);
        a3 = bf16_raw_to_f32((unsigned short)hv[3]);
        a4 = bf16_raw_to_f32((unsigned short)hv[4]);
        a5 = bf16_raw_to_f32((unsigned short)hv[5]);
        a6 = bf16_raw_to_f32((unsigned short)hv[6]);
        a7 = bf16_raw_to_f32((unsigned short)hv[7]);
      }
      *(float4*)&S[g][rl * STR_R + m * 8]     = (float4){a0, a1, a2, a3};
      *(float4*)&S[g][rl * STR_R + m * 8 + 4] = (float4){a4, a5, a6, a7};
    }
    __syncthreads();

    // ---- phase 2: K-split. wave w owns k in [32w, 32w+32); A reused for 8 nc ----
    for (int rl = 0; rl < rc; ++rl) {
      const int r = rbase + rl;
      const float* ap = &S[m][rl * STR_R + w * 32 + quad * 8];
      float4 f0 = *(const float4*)ap;
      float4 f1 = *(const float4*)(ap + 4);
      short8 a;
      a[0] = (short)f32_to_bf16_raw(f0.x);
      a[1] = (short)f32_to_bf16_raw(f0.y);
      a[2] = (short)f32_to_bf16_raw(f0.z);
      a[3] = (short)f32_to_bf16_raw(f0.w);
      a[4] = (short)f32_to_bf16_raw(f1.x);
      a[5] = (short)f32_to_bf16_raw(f1.y);
      a[6] = (short)f32_to_bf16_raw(f1.z);
      a[7] = (short)f32_to_bf16_raw(f1.w);
      const unsigned short* bp =
          WP + ((((size_t)(layer * NRELP + r) * 4 + w) * 8) * 64 + lane) * 8;
#pragma unroll
      for (int nc = 0; nc < 8; ++nc) {
        short8 b = *(const short8*)(bp + (size_t)nc * 64 * 8);
        acc[nc] = __builtin_amdgcn_mfma_f32_16x16x32_bf16(a, b, acc[nc], 0, 0, 0);
      }
    }
    __syncthreads();
  }

  // cross-wave K-reduction through LDS. red[w][row16][132] (reuse S region)
  float* red = &S[0][0];
#pragma unroll
  for (int nc = 0; nc < 8; ++nc)
#pragma unroll
    for (int i = 0; i < 4; ++i)
      red[w * (16 * 132) + (quad * 4 + i) * 132 + nc * 16 + m] = acc[nc][i];
  __syncthreads();

  {
    int row = tid >> 4, cb = (tid & 15) * 8;
    float4 b0 = *(const float4*)(bias + cb);
    float4 b1 = *(const float4*)(bias + cb + 4);
    float o[8];
#pragma unroll
    for (int j = 0; j < 8; ++j) {
      int col = cb + j;
      o[j] = red[0 * 2112 + row * 132 + col] + red[1 * 2112 + row * 132 + col]
           + red[2 * 2112 + row * 132 + col] + red[3 * 2112 + row * 132 + col];
    }
    o[0] += b0.x; o[1] += b0.y; o[2] += b0.z; o[3] += b0.w;
    o[4] += b1.x; o[5] += b1.y; o[6] += b1.z; o[7] += b1.w;
    if (outb) {
      short8 p;
#pragma unroll
      for (int j = 0; j < 8; ++j) p[j] = (short)f32_to_bf16_raw(o[j]);
      *(short8*)(outb + (size_t)(dst_base + row) * DIM + cb) = p;
    } else {
      float* op = outf + (size_t)(dst_base + row) * DIM + cb;
      *(float4*)op       = (float4){o[0], o[1], o[2], o[3]};
      *(float4*)(op + 4) = (float4){o[4], o[5], o[6], o[7]};
    }
  }
}

// ---------------- launch ----------------
extern "C" void kernel_launch(void* const* d_in, const int* in_sizes, int n_in,
                              void* d_out, int out_size, void* d_ws, size_t ws_size,
                              hipStream_t stream) {
  const float* h0     = (const float*)d_in[0];
  const float* W      = (const float*)d_in[1];
  const float* loop_w = (const float*)d_in[2];
  const float* bias   = (const float*)d_in[3];
  const int* esrc     = (const int*)d_in[4];
  const int* edst     = (const int*)d_in[5];
  const int* etyp     = (const int*)d_in[6];
  float* out = (float*)d_out;

  char* ws = (char*)d_ws;
  size_t off = 0;
  auto alloc = [&](size_t bytes) -> void* {
    void* p = ws + off;
    off = (off + bytes + 255) & ~(size_t)255;
    return p;
  };
  unsigned short* hb0   = (unsigned short*)alloc((size_t)NN * DIM * 2);   // 12.8 MB
  unsigned short* hb1   = (unsigned short*)alloc((size_t)NN * DIM * 2);   // 12.8 MB
  unsigned short* WP    = (unsigned short*)alloc((size_t)PACKED_ELEMS * 2);
  unsigned int*   cnt   = (unsigned int*)alloc((size_t)CELLS * 4);        // 6.4 MB
  unsigned int*   cofs  = (unsigned int*)alloc((size_t)(CELLS + 1) * 4);  // 6.4 MB
  unsigned int*   cursor= (unsigned int*)alloc((size_t)CELLS * 4);        // 6.4 MB
  unsigned int*   btot  = (unsigned int*)alloc((size_t)NBLK_A * 4);
  unsigned short* es    = (unsigned short*)alloc((size_t)NE * 2);         // 3.2 MB

  (void)hipMemsetAsync(cnt, 0, (size_t)CELLS * 4, stream);
  hist_kernel<<<NE / 256, 256, 0, stream>>>(edst, etyp, cnt, NE);
  scanA_kernel<<<NBLK_A, 256, 0, stream>>>(cnt, cofs, btot);
  scanB_kernel<<<1, 1024, 0, stream>>>(btot, cofs);
  scanC_kernel<<<NBLK_A, 256, 0, stream>>>(btot, cofs, cursor);
  scatter_kernel<<<NE / 256, 256, 0, stream>>>(esrc, edst, etyp, cursor, es, NE);

  pack_w_kernel<<<(PACKED_ELEMS + 255) / 256, 256, 0, stream>>>(W, loop_w, WP);
  cvt_bf16_kernel<<<(NN * DIM / 4 + 255) / 256, 256, 0, stream>>>(h0, hb0, NN * DIM / 4);

  rgcn_layer_kernel<<<NTILE, 256, 0, stream>>>(hb0, WP, bias, 0, cofs, es,
                                               nullptr, hb1);
  rgcn_layer_kernel<<<NTILE, 256, 0, stream>>>(hb1, WP, bias + DIM, 1, cofs, es,
                                               out, nullptr);
}